// Round 1
// baseline (793.393 us; speedup 1.0000x reference)
//
#include <hip/hip_runtime.h>
#include <hip/hip_bf16.h>

// Problem constants (B, C, T, H, KC, WIN) = (4, 512, 1024, 8, 64, 4)
#define Bdim 4
#define Cdim 512
#define Tdim 1024
#define Hn   8
#define KCd  64

// ---------------------------------------------------------------------------
// GEMM: out[b, m, n] = sum_k W[m,k] * X[b,k,n] + bias[m]
// Three weight/bias/out pointers selected by stacked row-tile index, so one
// launch does Q,K,V fused (M=1536). For the output projection pass the same
// pointers three times (M=512, sel always 0).
// Tile: 64x64 output, BK=16, 256 threads, 4x4 per thread.
// ---------------------------------------------------------------------------
__global__ __launch_bounds__(256) void gemm3_kernel(
    const float* __restrict__ w0, const float* __restrict__ w1, const float* __restrict__ w2,
    const float* __restrict__ bias0, const float* __restrict__ bias1, const float* __restrict__ bias2,
    const float* __restrict__ x,
    float* __restrict__ o0, float* __restrict__ o1, float* __restrict__ o2)
{
    const int tid = threadIdx.x;
    const int bx = blockIdx.x;              // n tile (16 of 64)
    const int m_tile = blockIdx.y * 64;     // stacked m tile
    const int b = blockIdx.z;

    const int sel = m_tile >> 9;            // which 512-block -> q/k/v
    const float* W  = sel == 0 ? w0 : (sel == 1 ? w1 : w2);
    const float* Bv = sel == 0 ? bias0 : (sel == 1 ? bias1 : bias2);
    float* O        = sel == 0 ? o0 : (sel == 1 ? o1 : o2);
    const int m0 = m_tile & 511;

    const float* Xb = x + (size_t)b * Cdim * Tdim;
    float* Ob = O + (size_t)b * Cdim * Tdim;

    __shared__ float As[16][65];   // [k][m], +1 pad
    __shared__ float Bs[16][64];   // [k][n]

    const int tx = tid & 15, ty = tid >> 4;

    float acc[4][4] = {{0.f}};

    const int a_m = tid >> 2;             // 0..63
    const int a_k = (tid & 3) << 2;       // 0,4,8,12
    const int b_k = tid >> 4;             // 0..15
    const int b_n = (tid & 15) << 2;      // 0..60

    for (int kk = 0; kk < Cdim; kk += 16) {
        float4 av = *(const float4*)(W + (size_t)(m0 + a_m) * Cdim + kk + a_k);
        float4 bv = *(const float4*)(Xb + (size_t)(kk + b_k) * Tdim + bx * 64 + b_n);
        __syncthreads();   // protect previous iteration's LDS reads
        As[a_k + 0][a_m] = av.x;
        As[a_k + 1][a_m] = av.y;
        As[a_k + 2][a_m] = av.z;
        As[a_k + 3][a_m] = av.w;
        *(float4*)&Bs[b_k][b_n] = bv;
        __syncthreads();
        #pragma unroll
        for (int k = 0; k < 16; ++k) {
            float a[4], bb[4];
            #pragma unroll
            for (int i = 0; i < 4; ++i) a[i] = As[k][ty * 4 + i];
            #pragma unroll
            for (int j = 0; j < 4; ++j) bb[j] = Bs[k][tx * 4 + j];
            #pragma unroll
            for (int i = 0; i < 4; ++i)
                #pragma unroll
                for (int j = 0; j < 4; ++j)
                    acc[i][j] += a[i] * bb[j];
        }
    }

    #pragma unroll
    for (int i = 0; i < 4; ++i) {
        const int m = m0 + ty * 4 + i;
        const float bsum = Bv[m];
        float4 r;
        r.x = acc[i][0] + bsum;
        r.y = acc[i][1] + bsum;
        r.z = acc[i][2] + bsum;
        r.w = acc[i][3] + bsum;
        *(float4*)(Ob + (size_t)m * Tdim + bx * 64 + tx * 4) = r;
    }
}

// ---------------------------------------------------------------------------
// Attention: one workgroup handles 8 query rows of one (b,h).
// q,k,v layout: [B, C, T] with head h occupying channels [h*64, h*64+64).
// Exact softmax (full 1024-wide score rows in LDS).
// Relative-position terms are width-9 banded corrections:
//   scores[i,j] += inv * q[i]·ek[j-i+4]        for |j-i| <= 4
//   out[i,c]    += sum_e p[i,i+e-4] * ev[e,c]  for valid i+e-4
// ---------------------------------------------------------------------------
__global__ __launch_bounds__(256) void attn_kernel(
    const float* __restrict__ q, const float* __restrict__ k, const float* __restrict__ v,
    const float* __restrict__ ek,   // [9,64]
    const float* __restrict__ ev,   // [9,64]
    float* __restrict__ ctx)        // [B, C, T]
{
    const int tid = threadIdx.x;
    const int i0 = blockIdx.x * 8;
    const int h = blockIdx.y, b = blockIdx.z;

    __shared__ float qs[8][64];
    __shared__ float ps[8][1024];
    __shared__ float red_m[8][4];
    __shared__ float red_s[8][4];

    const size_t base = ((size_t)b * Cdim + h * KCd) * Tdim;
    const float* qb = q + base;
    const float* kb = k + base;
    const float* vb = v + base;

    // load q tile: qs[r][c] = qb[c*T + i0 + r]
    for (int idx = tid; idx < 512; idx += 256) {
        const int r = idx & 7, c = idx >> 3;
        qs[r][c] = qb[c * Tdim + i0 + r];
    }
    __syncthreads();

    // ---- scores: thread covers j = tid + 256*s, s=0..3, for all 8 rows ----
    float sc[8][4];
    #pragma unroll
    for (int r = 0; r < 8; ++r)
        #pragma unroll
        for (int s = 0; s < 4; ++s) sc[r][s] = 0.f;

    for (int c = 0; c < 64; ++c) {
        float kv[4];
        #pragma unroll
        for (int s = 0; s < 4; ++s) kv[s] = kb[c * Tdim + tid + 256 * s];
        #pragma unroll
        for (int r = 0; r < 8; ++r) {
            const float qc = qs[r][c];
            #pragma unroll
            for (int s = 0; s < 4; ++s) sc[r][s] += qc * kv[s];
        }
    }

    // banded rel-k term + scale by 1/sqrt(KC); keep scaled value in regs, store to LDS
    #pragma unroll
    for (int s = 0; s < 4; ++s) {
        const int j = tid + 256 * s;
        #pragma unroll
        for (int r = 0; r < 8; ++r) {
            const int i = i0 + r;
            const int d = j - i;
            float val = sc[r][s];
            if (d >= -4 && d <= 4) {
                const float* ekp = ek + (d + 4) * KCd;
                float extra = 0.f;
                for (int c = 0; c < 64; ++c) extra += qs[r][c] * ekp[c];
                val += extra;
            }
            val *= 0.125f;   // 1/sqrt(64)
            sc[r][s] = val;
        }
    }

    // ---- softmax (exact, two reductions, batched over rows) ----
    const int lane = tid & 63, wid = tid >> 6;

    #pragma unroll
    for (int r = 0; r < 8; ++r) {
        float m = fmaxf(fmaxf(sc[r][0], sc[r][1]), fmaxf(sc[r][2], sc[r][3]));
        #pragma unroll
        for (int off = 32; off > 0; off >>= 1) m = fmaxf(m, __shfl_down(m, off));
        if (lane == 0) red_m[r][wid] = m;
    }
    __syncthreads();

    #pragma unroll
    for (int r = 0; r < 8; ++r) {
        const float m = fmaxf(fmaxf(red_m[r][0], red_m[r][1]),
                              fmaxf(red_m[r][2], red_m[r][3]));
        float s = 0.f;
        #pragma unroll
        for (int ss = 0; ss < 4; ++ss) {
            const float e = __expf(sc[r][ss] - m);
            ps[r][tid + 256 * ss] = e;
            s += e;
        }
        #pragma unroll
        for (int off = 32; off > 0; off >>= 1) s += __shfl_down(s, off);
        if (lane == 0) red_s[r][wid] = s;
    }
    __syncthreads();

    float rl[8];
    #pragma unroll
    for (int r = 0; r < 8; ++r) {
        const float l = red_s[r][0] + red_s[r][1] + red_s[r][2] + red_s[r][3];
        rl[r] = 1.f / l;
    }

    // ---- output: thread (c = tid>>2, quarter = tid&3) sums its j-quarter ----
    const int c = tid >> 2;
    const int quarter = tid & 3;
    float o[8] = {0.f, 0.f, 0.f, 0.f, 0.f, 0.f, 0.f, 0.f};
    const float* vrow = vb + c * Tdim;
    for (int jj = 0; jj < 256; ++jj) {
        // stagger start per quarter so the 4 distinct LDS addresses per wave
        // land in different banks (j differs by 256 -> same bank otherwise)
        const int j = (quarter << 8) | ((jj + (quarter << 3)) & 255);
        const float vj = vrow[j];
        #pragma unroll
        for (int r = 0; r < 8; ++r) o[r] += ps[r][j] * vj;
    }

    // reduce the 4 quarters (adjacent lanes)
    #pragma unroll
    for (int r = 0; r < 8; ++r) {
        o[r] += __shfl_xor(o[r], 1);
        o[r] += __shfl_xor(o[r], 2);
    }

    if (quarter == 0) {
        #pragma unroll
        for (int r = 0; r < 8; ++r) {
            const int i = i0 + r;
            float band = 0.f;
            #pragma unroll
            for (int e = 0; e < 9; ++e) {
                const int j = i + e - 4;
                if (j >= 0 && j < Tdim) band += ps[r][j] * ev[e * KCd + c];
            }
            ctx[base + c * Tdim + i] = (o[r] + band) * rl[r];
        }
    }
}

// ---------------------------------------------------------------------------
extern "C" void kernel_launch(void* const* d_in, const int* in_sizes, int n_in,
                              void* d_out, int out_size, void* d_ws, size_t ws_size,
                              hipStream_t stream) {
    const float* x  = (const float*)d_in[0];
    const float* wq = (const float*)d_in[1];
    const float* bq = (const float*)d_in[2];
    const float* wk = (const float*)d_in[3];
    const float* bk = (const float*)d_in[4];
    const float* wv = (const float*)d_in[5];
    const float* bv = (const float*)d_in[6];
    const float* wo = (const float*)d_in[7];
    const float* bo = (const float*)d_in[8];
    const float* ek = (const float*)d_in[9];
    const float* ev = (const float*)d_in[10];
    float* out = (float*)d_out;

    const size_t plane = (size_t)Bdim * Cdim * Tdim;  // 2M floats = 8 MB
    float* qbuf = (float*)d_ws;
    float* kbuf = qbuf + plane;
    float* vbuf = kbuf + plane;
    float* cbuf = vbuf + plane;

    // QKV projection: stacked M = 1536
    gemm3_kernel<<<dim3(16, 24, Bdim), 256, 0, stream>>>(
        wq, wk, wv, bq, bk, bv, x, qbuf, kbuf, vbuf);

    // attention with banded relative terms
    attn_kernel<<<dim3(Tdim / 8, Hn, Bdim), 256, 0, stream>>>(
        qbuf, kbuf, vbuf, ek, ev, cbuf);

    // output projection: M = 512 (sel always 0)
    gemm3_kernel<<<dim3(16, 8, Bdim), 256, 0, stream>>>(
        wo, wo, wo, bo, bo, bo, cbuf, out, out, out);
}

// Round 2
// 438.417 us; speedup vs baseline: 1.8097x; 1.8097x over previous
//
#include <hip/hip_runtime.h>
#include <hip/hip_bf16.h>

// Problem constants (B, C, T, H, KC, WIN) = (4, 512, 1024, 8, 64, 4)
#define Bdim 4
#define Cdim 512
#define Tdim 1024
#define Hn   8
#define KCd  64

// ---------------------------------------------------------------------------
// GEMM: out[b, m, n] = sum_k W[m,k] * X[b,k,n] + bias[m]
// sel 0/1 write natural [B,C,T]; sel 2 (V) writes transposed [B,H,T,KC] so
// the attention PV phase can stage V tiles into LDS conflict-free.
// ---------------------------------------------------------------------------
__global__ __launch_bounds__(256) void gemm3_kernel(
    const float* __restrict__ w0, const float* __restrict__ w1, const float* __restrict__ w2,
    const float* __restrict__ bias0, const float* __restrict__ bias1, const float* __restrict__ bias2,
    const float* __restrict__ x,
    float* __restrict__ o0, float* __restrict__ o1, float* __restrict__ o2)
{
    const int tid = threadIdx.x;
    const int bx = blockIdx.x;              // n tile (16 of 64)
    const int m_tile = blockIdx.y * 64;     // stacked m tile
    const int b = blockIdx.z;

    const int sel = m_tile >> 9;            // which 512-block -> q/k/v
    const float* W  = sel == 0 ? w0 : (sel == 1 ? w1 : w2);
    const float* Bv = sel == 0 ? bias0 : (sel == 1 ? bias1 : bias2);
    float* O        = sel == 0 ? o0 : (sel == 1 ? o1 : o2);
    const int m0 = m_tile & 511;

    const float* Xb = x + (size_t)b * Cdim * Tdim;
    float* Ob = O + (size_t)b * Cdim * Tdim;

    __shared__ float As[16][65];   // [k][m], +1 pad
    __shared__ float Bs[16][64];   // [k][n]

    const int tx = tid & 15, ty = tid >> 4;

    float acc[4][4] = {{0.f}};

    const int a_m = tid >> 2;             // 0..63
    const int a_k = (tid & 3) << 2;       // 0,4,8,12
    const int b_k = tid >> 4;             // 0..15
    const int b_n = (tid & 15) << 2;      // 0..60

    for (int kk = 0; kk < Cdim; kk += 16) {
        float4 av = *(const float4*)(W + (size_t)(m0 + a_m) * Cdim + kk + a_k);
        float4 bv = *(const float4*)(Xb + (size_t)(kk + b_k) * Tdim + bx * 64 + b_n);
        __syncthreads();   // protect previous iteration's LDS reads
        As[a_k + 0][a_m] = av.x;
        As[a_k + 1][a_m] = av.y;
        As[a_k + 2][a_m] = av.z;
        As[a_k + 3][a_m] = av.w;
        *(float4*)&Bs[b_k][b_n] = bv;
        __syncthreads();
        #pragma unroll
        for (int k = 0; k < 16; ++k) {
            float a[4], bb[4];
            #pragma unroll
            for (int i = 0; i < 4; ++i) a[i] = As[k][ty * 4 + i];
            #pragma unroll
            for (int j = 0; j < 4; ++j) bb[j] = Bs[k][tx * 4 + j];
            #pragma unroll
            for (int i = 0; i < 4; ++i)
                #pragma unroll
                for (int j = 0; j < 4; ++j)
                    acc[i][j] += a[i] * bb[j];
        }
    }

    if (sel == 2) {
        // transposed store: vT[((b*H + head)*T + n)*KC + c_in_head]
        const int head = m0 >> 6;           // m-tiles are 64-aligned: whole tile in one head
        float bv4[4];
        #pragma unroll
        for (int i = 0; i < 4; ++i) bv4[i] = Bv[m0 + ty * 4 + i];
        float* vTb = o2 + ((size_t)(b * Hn + head) * Tdim) * KCd;
        #pragma unroll
        for (int jj = 0; jj < 4; ++jj) {
            const int n = bx * 64 + tx * 4 + jj;
            float4 r;
            r.x = acc[0][jj] + bv4[0];
            r.y = acc[1][jj] + bv4[1];
            r.z = acc[2][jj] + bv4[2];
            r.w = acc[3][jj] + bv4[3];
            *(float4*)(vTb + (size_t)n * KCd + ty * 4) = r;
        }
    } else {
        #pragma unroll
        for (int i = 0; i < 4; ++i) {
            const int m = m0 + ty * 4 + i;
            const float bsum = Bv[m];
            float4 r;
            r.x = acc[i][0] + bsum;
            r.y = acc[i][1] + bsum;
            r.z = acc[i][2] + bsum;
            r.w = acc[i][3] + bsum;
            *(float4*)(Ob + (size_t)m * Tdim + bx * 64 + tx * 4) = r;
        }
    }
}

// ---------------------------------------------------------------------------
// Flash-style attention with banded relative terms.
// 64 query rows per block, 256 threads, j-tiles of 64, online softmax.
// LDS row stride 68 floats: all access patterns are at the wave64 phase floor.
// ks buffer is reused as ps (P^T) between the S and PV phases of each tile.
// Thread map (both phases): tx=tid&15, ty=tid>>4; m = 4*ty+ii; j/c = 4*tx+xx.
// ---------------------------------------------------------------------------
__global__ __launch_bounds__(256) void attn_flash(
    const float* __restrict__ q,    // [B,C,T]
    const float* __restrict__ k,    // [B,C,T]
    const float* __restrict__ vT,   // [B,H,T,KC]
    const float* __restrict__ ek,   // [9,64]
    const float* __restrict__ ev,   // [9,64]
    float* __restrict__ ctx)        // [B,C,T]
{
    const int tid = threadIdx.x;
    const int tx = tid & 15, ty = tid >> 4;
    const int i0 = blockIdx.x * 64;
    const int h = blockIdx.y, b = blockIdx.z;

    __shared__ float qs[64][68];     // [c][m]
    __shared__ float ks_ps[64][68];  // S phase: [c][j]; PV phase: [j][m]
    __shared__ float vs[64][68];     // [j][c]
    __shared__ float rk[64][12];     // q·ek table  [m][e]
    __shared__ float evs[9][68];     // [e][c]

    const size_t base = ((size_t)b * Cdim + h * KCd) * Tdim;
    const float* qb = q + base;
    const float* kb = k + base;
    const float* vTb = vT + ((size_t)(b * Hn + h) * Tdim) * KCd;

    // stage q tile: qs[c][m] = q[c][i0+m]
    #pragma unroll
    for (int p = 0; p < 4; ++p) {
        const int c = ty + 16 * p;
        *(float4*)&qs[c][tx * 4] = *(const float4*)(qb + (size_t)c * Tdim + i0 + tx * 4);
    }
    for (int idx = tid; idx < 9 * 64; idx += 256) {
        const int e = idx >> 6, c = idx & 63;
        evs[e][c] = ev[idx];
    }
    __syncthreads();

    // rk[m][e] = q[m]·ek[e]  (raw, pre-scale)
    for (int idx = tid; idx < 576; idx += 256) {
        const int m = idx / 9, e = idx - m * 9;
        float s = 0.f;
        for (int c = 0; c < 64; ++c) s += qs[c][m] * ek[e * 64 + c];
        rk[m][e] = s;
    }
    // (visibility of rk covered by the barrier inside the first loop iteration)

    float m_run[4], l_run[4], O[4][4];
    #pragma unroll
    for (int ii = 0; ii < 4; ++ii) {
        m_run[ii] = -1e30f; l_run[ii] = 0.f;
        #pragma unroll
        for (int cc = 0; cc < 4; ++cc) O[ii][cc] = 0.f;
    }

    // prefetch tile 0 into registers
    float4 kreg[4], vreg[4];
    #pragma unroll
    for (int p = 0; p < 4; ++p) {
        kreg[p] = *(const float4*)(kb + (size_t)(ty + 16 * p) * Tdim + 0 + tx * 4);
        vreg[p] = *(const float4*)(vTb + (size_t)(0 + ty + 16 * p) * KCd + tx * 4);
    }

    for (int t = 0; t < 16; ++t) {
        const int j0 = t * 64;
        // stage tile t from prefetch regs (prev PV finished at loop-end barrier)
        #pragma unroll
        for (int p = 0; p < 4; ++p) {
            *(float4*)&ks_ps[ty + 16 * p][tx * 4] = kreg[p];
            *(float4*)&vs[ty + 16 * p][tx * 4]    = vreg[p];
        }
        __syncthreads();                                  // A: tile ready (t=0: also rk/evs)

        // prefetch tile t+1
        if (t < 15) {
            const int j1 = j0 + 64;
            #pragma unroll
            for (int p = 0; p < 4; ++p) {
                kreg[p] = *(const float4*)(kb + (size_t)(ty + 16 * p) * Tdim + j1 + tx * 4);
                vreg[p] = *(const float4*)(vTb + (size_t)(j1 + ty + 16 * p) * KCd + tx * 4);
            }
        }

        // ---- S tile: S[ii][jj] = q[m]·k[j], m=4ty+ii, j=j0+4tx+jj ----
        float S[4][4] = {{0.f}};
        for (int c = 0; c < 64; ++c) {
            float4 aq = *(const float4*)&qs[c][ty * 4];
            float4 bk = *(const float4*)&ks_ps[c][tx * 4];
            const float a[4]  = {aq.x, aq.y, aq.z, aq.w};
            const float bb[4] = {bk.x, bk.y, bk.z, bk.w};
            #pragma unroll
            for (int ii = 0; ii < 4; ++ii)
                #pragma unroll
                for (int jj = 0; jj < 4; ++jj)
                    S[ii][jj] += a[ii] * bb[jj];
        }
        const int dbase = j0 - i0;
        if (dbase >= -67 && dbase <= 67) {     // banded rel-k add (3 tiles only)
            #pragma unroll
            for (int ii = 0; ii < 4; ++ii)
                #pragma unroll
                for (int jj = 0; jj < 4; ++jj) {
                    const int d = dbase + (4 * tx + jj) - (4 * ty + ii);
                    if ((unsigned)(d + 4) < 9u) S[ii][jj] += rk[4 * ty + ii][d + 4];
                }
        }
        #pragma unroll
        for (int ii = 0; ii < 4; ++ii)
            #pragma unroll
            for (int jj = 0; jj < 4; ++jj) S[ii][jj] *= 0.125f;

        // ---- online softmax update (row group = 16 consecutive lanes) ----
        float alpha[4];
        #pragma unroll
        for (int ii = 0; ii < 4; ++ii) {
            float mt = fmaxf(fmaxf(S[ii][0], S[ii][1]), fmaxf(S[ii][2], S[ii][3]));
            mt = fmaxf(mt, __shfl_xor(mt, 1));
            mt = fmaxf(mt, __shfl_xor(mt, 2));
            mt = fmaxf(mt, __shfl_xor(mt, 4));
            mt = fmaxf(mt, __shfl_xor(mt, 8));
            const float mn = fmaxf(m_run[ii], mt);
            alpha[ii] = __expf(m_run[ii] - mn);
            float rs = 0.f;
            #pragma unroll
            for (int jj = 0; jj < 4; ++jj) {
                const float e = __expf(S[ii][jj] - mn);
                S[ii][jj] = e;
                rs += e;
            }
            rs += __shfl_xor(rs, 1);
            rs += __shfl_xor(rs, 2);
            rs += __shfl_xor(rs, 4);
            rs += __shfl_xor(rs, 8);
            l_run[ii] = l_run[ii] * alpha[ii] + rs;
            m_run[ii] = mn;
        }

        __syncthreads();                                  // B: all S-phase ks reads done
        // write P^T into ks_ps: ps[j][m]
        #pragma unroll
        for (int jj = 0; jj < 4; ++jj) {
            float4 pcol;
            pcol.x = S[0][jj]; pcol.y = S[1][jj]; pcol.z = S[2][jj]; pcol.w = S[3][jj];
            *(float4*)&ks_ps[4 * tx + jj][4 * ty] = pcol;
        }
        __syncthreads();                                  // C: ps ready

        // ---- PV: O[ii][cc] (m=4ty+ii, c=4tx+cc) ----
        #pragma unroll
        for (int ii = 0; ii < 4; ++ii)
            #pragma unroll
            for (int cc = 0; cc < 4; ++cc) O[ii][cc] *= alpha[ii];

        for (int j = 0; j < 64; ++j) {
            float4 p4 = *(const float4*)&ks_ps[j][4 * ty];
            float4 v4 = *(const float4*)&vs[j][4 * tx];
            const float pv[4] = {p4.x, p4.y, p4.z, p4.w};
            const float vv[4] = {v4.x, v4.y, v4.z, v4.w};
            #pragma unroll
            for (int ii = 0; ii < 4; ++ii)
                #pragma unroll
                for (int cc = 0; cc < 4; ++cc)
                    O[ii][cc] += pv[ii] * vv[cc];
        }

        if (dbase >= -67 && dbase <= 67) {     // banded rel-v term via ps
            #pragma unroll
            for (int ii = 0; ii < 4; ++ii) {
                const int i = i0 + 4 * ty + ii;
                #pragma unroll
                for (int d = -4; d <= 4; ++d) {
                    const int jl = i + d - j0;
                    if ((unsigned)jl < 64u) {
                        const float pj = ks_ps[jl][4 * ty + ii];
                        float4 e4 = *(const float4*)&evs[d + 4][tx * 4];
                        O[ii][0] += pj * e4.x;
                        O[ii][1] += pj * e4.y;
                        O[ii][2] += pj * e4.z;
                        O[ii][3] += pj * e4.w;
                    }
                }
            }
        }
        __syncthreads();                                  // D: PV reads done
    }

    // ---- finalize: ctx[c][i] = O[m][c] / l[m] ----
    float rl[4];
    #pragma unroll
    for (int ii = 0; ii < 4; ++ii) rl[ii] = 1.f / l_run[ii];
    #pragma unroll
    for (int cc = 0; cc < 4; ++cc) {
        float4 o4;
        o4.x = O[0][cc] * rl[0];
        o4.y = O[1][cc] * rl[1];
        o4.z = O[2][cc] * rl[2];
        o4.w = O[3][cc] * rl[3];
        *(float4*)(ctx + base + (size_t)(4 * tx + cc) * Tdim + i0 + 4 * ty) = o4;
    }
}

// ---------------------------------------------------------------------------
extern "C" void kernel_launch(void* const* d_in, const int* in_sizes, int n_in,
                              void* d_out, int out_size, void* d_ws, size_t ws_size,
                              hipStream_t stream) {
    const float* x  = (const float*)d_in[0];
    const float* wq = (const float*)d_in[1];
    const float* bq = (const float*)d_in[2];
    const float* wk = (const float*)d_in[3];
    const float* bk = (const float*)d_in[4];
    const float* wv = (const float*)d_in[5];
    const float* bv = (const float*)d_in[6];
    const float* wo = (const float*)d_in[7];
    const float* bo = (const float*)d_in[8];
    const float* ek = (const float*)d_in[9];
    const float* ev = (const float*)d_in[10];
    float* out = (float*)d_out;

    const size_t plane = (size_t)Bdim * Cdim * Tdim;  // 2M floats = 8 MB
    float* qbuf  = (float*)d_ws;
    float* kbuf  = qbuf + plane;
    float* vTbuf = kbuf + plane;
    float* cbuf  = vTbuf + plane;

    // QKV projection: stacked M = 1536; V written transposed [B,H,T,KC]
    gemm3_kernel<<<dim3(16, 24, Bdim), 256, 0, stream>>>(
        wq, wk, wv, bq, bk, bv, x, qbuf, kbuf, vTbuf);

    // flash attention with banded relative terms
    attn_flash<<<dim3(Tdim / 64, Hn, Bdim), 256, 0, stream>>>(
        qbuf, kbuf, vTbuf, ek, ev, cbuf);

    // output projection: M = 512 (sel always 0)
    gemm3_kernel<<<dim3(16, 8, Bdim), 256, 0, stream>>>(
        wo, wo, wo, bo, bo, bo, cbuf, out, out, out);
}

// Round 3
// 302.531 us; speedup vs baseline: 2.6225x; 1.4492x over previous
//
#include <hip/hip_runtime.h>
#include <hip/hip_bf16.h>

// Problem constants (B, C, T, H, KC, WIN) = (4, 512, 1024, 8, 64, 4)
#define Bdim 4
#define Cdim 512
#define Tdim 1024
#define Hn   8
#define KCd  64

typedef __attribute__((ext_vector_type(8))) short bf16x8;   // 8 bf16 = 4 VGPR
typedef __attribute__((ext_vector_type(4))) float f32x4;    // MFMA C/D

__device__ inline unsigned short f32_bf16_rne(float f) {
    unsigned u = __float_as_uint(f);
    u += 0x7FFFu + ((u >> 16) & 1u);
    return (unsigned short)(u >> 16);
}
__device__ inline float bf16_f32(unsigned short h) {
    return __uint_as_float(((unsigned)h) << 16);
}

// ---------------------------------------------------------------------------
// bf16x3 MFMA GEMM: out[b,m,n] = sum_k W[m,k] * X[b,k,n] + bias[m]
// fp32 accuracy via split: a = hi + lo (both bf16); product = hi*hi + hi*lo
// + lo*hi (3 MFMAs, lo*lo dropped ~2^-18).
// Tile BM=128 (stacked m), BN=64 (t), BK=32. 256 threads = 4 waves (2x2),
// each wave 64m x 32n = 4x2 MFMA tiles of 16x16x32.
// A-op = W (k-contiguous, no transpose); B-op = X transpose-staged [n][k].
// LDS k-stride 40 bf16 (80 B = 5 x 16 B, odd) -> b128 ops at phase floor.
// D layout (m89-verified): col(lane&15)=n, row(quad*4+reg)=m.
// sel 0/1 store natural [C,T]; sel 2 stores V transposed [B,H,T,KC].
// ---------------------------------------------------------------------------
#define BM 128
#define BN 64
#define BK 32
#define LDK 40

__global__ __launch_bounds__(256) void gemm3_mfma(
    const float* __restrict__ w0, const float* __restrict__ w1, const float* __restrict__ w2,
    const float* __restrict__ b0, const float* __restrict__ b1, const float* __restrict__ b2,
    const float* __restrict__ x,
    float* __restrict__ o0, float* __restrict__ o1, float* __restrict__ o2)
{
    __shared__ unsigned short Whi[BM][LDK], Wlo[BM][LDK];
    __shared__ unsigned short Xhi[BN][LDK], Xlo[BN][LDK];

    const int tid = threadIdx.x;
    const int bx = blockIdx.x;            // n tile (16)
    const int by = blockIdx.y;            // stacked m tile
    const int b  = blockIdx.z;

    const int m_tile = by * BM;
    const int sel = m_tile >> 9;
    const float* W  = sel == 0 ? w0 : (sel == 1 ? w1 : w2);
    const float* Bv = sel == 0 ? b0 : (sel == 1 ? b1 : b2);
    const int m0 = m_tile & 511;
    const int n0 = bx * BN;

    const float* Xb = x + (size_t)b * Cdim * Tdim;

    const int lane = tid & 63, wid = tid >> 6;
    const int wm = (wid & 1) * 64, wn = (wid >> 1) * 32;
    const int l15 = lane & 15, quad = lane >> 4;

    // staging maps
    const int wk4 = (tid & 7) * 4;        // W: k-float4 index (0..28)
    const int wmr = tid >> 3;             // W: row 0..31 (+32 per pass)
    const int xn  = tid & 63;             // X: n within tile
    const int xo  = tid >> 6;             // X: k octet (0..3)

    f32x4 acc[4][2];
    #pragma unroll
    for (int i = 0; i < 4; ++i)
        #pragma unroll
        for (int j = 0; j < 2; ++j) acc[i][j] = (f32x4){0.f, 0.f, 0.f, 0.f};

    for (int k0 = 0; k0 < Cdim; k0 += BK) {
        __syncthreads();   // protect previous iteration's LDS reads

        // ---- stage W tile: 128m x 32k, coalesced float4 along k ----
        #pragma unroll
        for (int p = 0; p < 4; ++p) {
            const int m = wmr + p * 32;
            float4 wv = *(const float4*)(W + (size_t)(m0 + m) * Cdim + k0 + wk4);
            ushort4 hi, lo;
            hi.x = f32_bf16_rne(wv.x); lo.x = f32_bf16_rne(wv.x - bf16_f32(hi.x));
            hi.y = f32_bf16_rne(wv.y); lo.y = f32_bf16_rne(wv.y - bf16_f32(hi.y));
            hi.z = f32_bf16_rne(wv.z); lo.z = f32_bf16_rne(wv.z - bf16_f32(hi.z));
            hi.w = f32_bf16_rne(wv.w); lo.w = f32_bf16_rne(wv.w - bf16_f32(hi.w));
            *(ushort4*)&Whi[m][wk4] = hi;
            *(ushort4*)&Wlo[m][wk4] = lo;
        }

        // ---- stage X^T tile: LDS [n][k] from X [k][n]; coalesced dword ----
        {
            float xv[8];
            #pragma unroll
            for (int kk = 0; kk < 8; ++kk)
                xv[kk] = Xb[(size_t)(k0 + xo * 8 + kk) * Tdim + n0 + xn];
            ushort4 hi0, hi1, lo0, lo1;
            unsigned short h;
            h = f32_bf16_rne(xv[0]); hi0.x = h; lo0.x = f32_bf16_rne(xv[0] - bf16_f32(h));
            h = f32_bf16_rne(xv[1]); hi0.y = h; lo0.y = f32_bf16_rne(xv[1] - bf16_f32(h));
            h = f32_bf16_rne(xv[2]); hi0.z = h; lo0.z = f32_bf16_rne(xv[2] - bf16_f32(h));
            h = f32_bf16_rne(xv[3]); hi0.w = h; lo0.w = f32_bf16_rne(xv[3] - bf16_f32(h));
            h = f32_bf16_rne(xv[4]); hi1.x = h; lo1.x = f32_bf16_rne(xv[4] - bf16_f32(h));
            h = f32_bf16_rne(xv[5]); hi1.y = h; lo1.y = f32_bf16_rne(xv[5] - bf16_f32(h));
            h = f32_bf16_rne(xv[6]); hi1.z = h; lo1.z = f32_bf16_rne(xv[6] - bf16_f32(h));
            h = f32_bf16_rne(xv[7]); hi1.w = h; lo1.w = f32_bf16_rne(xv[7] - bf16_f32(h));
            *(ushort4*)&Xhi[xn][xo * 8]     = hi0;
            *(ushort4*)&Xhi[xn][xo * 8 + 4] = hi1;
            *(ushort4*)&Xlo[xn][xo * 8]     = lo0;
            *(ushort4*)&Xlo[xn][xo * 8 + 4] = lo1;
        }
        __syncthreads();

        // ---- fragments + MFMA ----
        bf16x8 ahi[4], alo[4], bhi[2], blo[2];
        #pragma unroll
        for (int mt = 0; mt < 4; ++mt) {
            ahi[mt] = *(const bf16x8*)&Whi[wm + mt * 16 + l15][quad * 8];
            alo[mt] = *(const bf16x8*)&Wlo[wm + mt * 16 + l15][quad * 8];
        }
        #pragma unroll
        for (int nt = 0; nt < 2; ++nt) {
            bhi[nt] = *(const bf16x8*)&Xhi[wn + nt * 16 + l15][quad * 8];
            blo[nt] = *(const bf16x8*)&Xlo[wn + nt * 16 + l15][quad * 8];
        }
        #pragma unroll
        for (int mt = 0; mt < 4; ++mt)
            #pragma unroll
            for (int nt = 0; nt < 2; ++nt) {
                f32x4 c = acc[mt][nt];
                c = __builtin_amdgcn_mfma_f32_16x16x32_bf16(ahi[mt], bhi[nt], c, 0, 0, 0);
                c = __builtin_amdgcn_mfma_f32_16x16x32_bf16(ahi[mt], blo[nt], c, 0, 0, 0);
                c = __builtin_amdgcn_mfma_f32_16x16x32_bf16(alo[mt], bhi[nt], c, 0, 0, 0);
                acc[mt][nt] = c;
            }
    }

    // ---- epilogue: bias + store ----
    if (sel == 2) {
        // V: store transposed to o2 as [B,H,T,KC]; lane's 4 regs are 4
        // consecutive channels -> float4 per (tile, n).
        #pragma unroll
        for (int mt = 0; mt < 4; ++mt) {
            const int mv = m0 + wm + mt * 16 + quad * 4;   // 0..511, mult of 4
            const int head = mv >> 6, c0 = mv & 63;
            float bb[4];
            #pragma unroll
            for (int r = 0; r < 4; ++r) bb[r] = Bv[mv + r];
            float* vTb = o2 + ((size_t)(b * Hn + head) * Tdim) * KCd;
            #pragma unroll
            for (int nt = 0; nt < 2; ++nt) {
                const int t = n0 + wn + nt * 16 + l15;
                float4 r4;
                r4.x = acc[mt][nt][0] + bb[0];
                r4.y = acc[mt][nt][1] + bb[1];
                r4.z = acc[mt][nt][2] + bb[2];
                r4.w = acc[mt][nt][3] + bb[3];
                *(float4*)(vTb + (size_t)t * KCd + c0) = r4;
            }
        }
    } else {
        float* Ob = (sel == 0 ? o0 : o1) + (size_t)b * Cdim * Tdim;
        #pragma unroll
        for (int mt = 0; mt < 4; ++mt) {
            const int mb = m0 + wm + mt * 16 + quad * 4;
            float bb[4];
            #pragma unroll
            for (int r = 0; r < 4; ++r) bb[r] = Bv[mb + r];
            #pragma unroll
            for (int nt = 0; nt < 2; ++nt) {
                const int t = n0 + wn + nt * 16 + l15;
                #pragma unroll
                for (int r = 0; r < 4; ++r)
                    Ob[(size_t)(mb + r) * Tdim + t] = acc[mt][nt][r] + bb[r];
            }
        }
    }
}

// ---------------------------------------------------------------------------
// Flash-style attention with banded relative terms (unchanged from round 2).
// ---------------------------------------------------------------------------
__global__ __launch_bounds__(256) void attn_flash(
    const float* __restrict__ q,    // [B,C,T]
    const float* __restrict__ k,    // [B,C,T]
    const float* __restrict__ vT,   // [B,H,T,KC]
    const float* __restrict__ ek,   // [9,64]
    const float* __restrict__ ev,   // [9,64]
    float* __restrict__ ctx)        // [B,C,T]
{
    const int tid = threadIdx.x;
    const int tx = tid & 15, ty = tid >> 4;
    const int i0 = blockIdx.x * 64;
    const int h = blockIdx.y, b = blockIdx.z;

    __shared__ float qs[64][68];     // [c][m]
    __shared__ float ks_ps[64][68];  // S phase: [c][j]; PV phase: [j][m]
    __shared__ float vs[64][68];     // [j][c]
    __shared__ float rk[64][12];     // q·ek table  [m][e]
    __shared__ float evs[9][68];     // [e][c]

    const size_t base = ((size_t)b * Cdim + h * KCd) * Tdim;
    const float* qb = q + base;
    const float* kb = k + base;
    const float* vTb = vT + ((size_t)(b * Hn + h) * Tdim) * KCd;

    #pragma unroll
    for (int p = 0; p < 4; ++p) {
        const int c = ty + 16 * p;
        *(float4*)&qs[c][tx * 4] = *(const float4*)(qb + (size_t)c * Tdim + i0 + tx * 4);
    }
    for (int idx = tid; idx < 9 * 64; idx += 256) {
        const int e = idx >> 6, c = idx & 63;
        evs[e][c] = ev[idx];
    }
    __syncthreads();

    for (int idx = tid; idx < 576; idx += 256) {
        const int m = idx / 9, e = idx - m * 9;
        float s = 0.f;
        for (int c = 0; c < 64; ++c) s += qs[c][m] * ek[e * 64 + c];
        rk[m][e] = s;
    }

    float m_run[4], l_run[4], O[4][4];
    #pragma unroll
    for (int ii = 0; ii < 4; ++ii) {
        m_run[ii] = -1e30f; l_run[ii] = 0.f;
        #pragma unroll
        for (int cc = 0; cc < 4; ++cc) O[ii][cc] = 0.f;
    }

    float4 kreg[4], vreg[4];
    #pragma unroll
    for (int p = 0; p < 4; ++p) {
        kreg[p] = *(const float4*)(kb + (size_t)(ty + 16 * p) * Tdim + 0 + tx * 4);
        vreg[p] = *(const float4*)(vTb + (size_t)(0 + ty + 16 * p) * KCd + tx * 4);
    }

    for (int t = 0; t < 16; ++t) {
        const int j0 = t * 64;
        #pragma unroll
        for (int p = 0; p < 4; ++p) {
            *(float4*)&ks_ps[ty + 16 * p][tx * 4] = kreg[p];
            *(float4*)&vs[ty + 16 * p][tx * 4]    = vreg[p];
        }
        __syncthreads();

        if (t < 15) {
            const int j1 = j0 + 64;
            #pragma unroll
            for (int p = 0; p < 4; ++p) {
                kreg[p] = *(const float4*)(kb + (size_t)(ty + 16 * p) * Tdim + j1 + tx * 4);
                vreg[p] = *(const float4*)(vTb + (size_t)(j1 + ty + 16 * p) * KCd + tx * 4);
            }
        }

        float S[4][4] = {{0.f}};
        for (int c = 0; c < 64; ++c) {
            float4 aq = *(const float4*)&qs[c][ty * 4];
            float4 bk = *(const float4*)&ks_ps[c][tx * 4];
            const float a[4]  = {aq.x, aq.y, aq.z, aq.w};
            const float bb[4] = {bk.x, bk.y, bk.z, bk.w};
            #pragma unroll
            for (int ii = 0; ii < 4; ++ii)
                #pragma unroll
                for (int jj = 0; jj < 4; ++jj)
                    S[ii][jj] += a[ii] * bb[jj];
        }
        const int dbase = j0 - i0;
        if (dbase >= -67 && dbase <= 67) {
            #pragma unroll
            for (int ii = 0; ii < 4; ++ii)
                #pragma unroll
                for (int jj = 0; jj < 4; ++jj) {
                    const int d = dbase + (4 * tx + jj) - (4 * ty + ii);
                    if ((unsigned)(d + 4) < 9u) S[ii][jj] += rk[4 * ty + ii][d + 4];
                }
        }
        #pragma unroll
        for (int ii = 0; ii < 4; ++ii)
            #pragma unroll
            for (int jj = 0; jj < 4; ++jj) S[ii][jj] *= 0.125f;

        float alpha[4];
        #pragma unroll
        for (int ii = 0; ii < 4; ++ii) {
            float mt = fmaxf(fmaxf(S[ii][0], S[ii][1]), fmaxf(S[ii][2], S[ii][3]));
            mt = fmaxf(mt, __shfl_xor(mt, 1));
            mt = fmaxf(mt, __shfl_xor(mt, 2));
            mt = fmaxf(mt, __shfl_xor(mt, 4));
            mt = fmaxf(mt, __shfl_xor(mt, 8));
            const float mn = fmaxf(m_run[ii], mt);
            alpha[ii] = __expf(m_run[ii] - mn);
            float rs = 0.f;
            #pragma unroll
            for (int jj = 0; jj < 4; ++jj) {
                const float e = __expf(S[ii][jj] - mn);
                S[ii][jj] = e;
                rs += e;
            }
            rs += __shfl_xor(rs, 1);
            rs += __shfl_xor(rs, 2);
            rs += __shfl_xor(rs, 4);
            rs += __shfl_xor(rs, 8);
            l_run[ii] = l_run[ii] * alpha[ii] + rs;
            m_run[ii] = mn;
        }

        __syncthreads();
        #pragma unroll
        for (int jj = 0; jj < 4; ++jj) {
            float4 pcol;
            pcol.x = S[0][jj]; pcol.y = S[1][jj]; pcol.z = S[2][jj]; pcol.w = S[3][jj];
            *(float4*)&ks_ps[4 * tx + jj][4 * ty] = pcol;
        }
        __syncthreads();

        #pragma unroll
        for (int ii = 0; ii < 4; ++ii)
            #pragma unroll
            for (int cc = 0; cc < 4; ++cc) O[ii][cc] *= alpha[ii];

        for (int j = 0; j < 64; ++j) {
            float4 p4 = *(const float4*)&ks_ps[j][4 * ty];
            float4 v4 = *(const float4*)&vs[j][4 * tx];
            const float pv[4] = {p4.x, p4.y, p4.z, p4.w};
            const float vv[4] = {v4.x, v4.y, v4.z, v4.w};
            #pragma unroll
            for (int ii = 0; ii < 4; ++ii)
                #pragma unroll
                for (int cc = 0; cc < 4; ++cc)
                    O[ii][cc] += pv[ii] * vv[cc];
        }

        if (dbase >= -67 && dbase <= 67) {
            #pragma unroll
            for (int ii = 0; ii < 4; ++ii) {
                const int i = i0 + 4 * ty + ii;
                #pragma unroll
                for (int d = -4; d <= 4; ++d) {
                    const int jl = i + d - j0;
                    if ((unsigned)jl < 64u) {
                        const float pj = ks_ps[jl][4 * ty + ii];
                        float4 e4 = *(const float4*)&evs[d + 4][tx * 4];
                        O[ii][0] += pj * e4.x;
                        O[ii][1] += pj * e4.y;
                        O[ii][2] += pj * e4.z;
                        O[ii][3] += pj * e4.w;
                    }
                }
            }
        }
        __syncthreads();
    }

    float rl[4];
    #pragma unroll
    for (int ii = 0; ii < 4; ++ii) rl[ii] = 1.f / l_run[ii];
    #pragma unroll
    for (int cc = 0; cc < 4; ++cc) {
        float4 o4;
        o4.x = O[0][cc] * rl[0];
        o4.y = O[1][cc] * rl[1];
        o4.z = O[2][cc] * rl[2];
        o4.w = O[3][cc] * rl[3];
        *(float4*)(ctx + base + (size_t)(4 * tx + cc) * Tdim + i0 + 4 * ty) = o4;
    }
}

// ---------------------------------------------------------------------------
extern "C" void kernel_launch(void* const* d_in, const int* in_sizes, int n_in,
                              void* d_out, int out_size, void* d_ws, size_t ws_size,
                              hipStream_t stream) {
    const float* x  = (const float*)d_in[0];
    const float* wq = (const float*)d_in[1];
    const float* bq = (const float*)d_in[2];
    const float* wk = (const float*)d_in[3];
    const float* bk = (const float*)d_in[4];
    const float* wv = (const float*)d_in[5];
    const float* bv = (const float*)d_in[6];
    const float* wo = (const float*)d_in[7];
    const float* bo = (const float*)d_in[8];
    const float* ek = (const float*)d_in[9];
    const float* ev = (const float*)d_in[10];
    float* out = (float*)d_out;

    const size_t plane = (size_t)Bdim * Cdim * Tdim;  // 2M floats = 8 MB
    float* qbuf  = (float*)d_ws;
    float* kbuf  = qbuf + plane;
    float* vTbuf = kbuf + plane;
    float* cbuf  = vTbuf + plane;

    // QKV projection: stacked M = 1536; V written transposed [B,H,T,KC]
    gemm3_mfma<<<dim3(Tdim / BN, 1536 / BM, Bdim), 256, 0, stream>>>(
        wq, wk, wv, bq, bk, bv, x, qbuf, kbuf, vTbuf);

    // flash attention with banded relative terms
    attn_flash<<<dim3(Tdim / 64, Hn, Bdim), 256, 0, stream>>>(
        qbuf, kbuf, vTbuf, ek, ev, cbuf);

    // output projection: M = 512 (sel always 0)
    gemm3_mfma<<<dim3(Tdim / BN, Cdim / BM, Bdim), 256, 0, stream>>>(
        wo, wo, wo, bo, bo, bo, cbuf, out, out, out);
}

// Round 4
// 237.778 us; speedup vs baseline: 3.3367x; 1.2723x over previous
//
#include <hip/hip_runtime.h>
#include <hip/hip_bf16.h>

// Problem constants (B, C, T, H, KC, WIN) = (4, 512, 1024, 8, 64, 4)
#define Bdim 4
#define Cdim 512
#define Tdim 1024
#define Hn   8
#define KCd  64

typedef __attribute__((ext_vector_type(8))) short bf16x8;   // 8 bf16 = 4 VGPR
typedef __attribute__((ext_vector_type(4))) float f32x4;    // MFMA C/D

__device__ __forceinline__ unsigned short f32_bf16_rne(float f) {
    unsigned u = __float_as_uint(f);
    u += 0x7FFFu + ((u >> 16) & 1u);
    return (unsigned short)(u >> 16);
}
__device__ __forceinline__ float bf16_f32(unsigned short h) {
    return __uint_as_float(((unsigned)h) << 16);
}

// 64x64 bf16 LDS tile, 16B-chunk XOR swizzle: row stride 64 ushorts (128 B),
// chunk (8 ushorts) index XOR'd with row&7. All frag reads / staged writes
// sit at the wave64 bank-phase floor (verified by hand for each pattern).
__device__ __forceinline__ int sw(int row, int col) {
    return (row << 6) + ((((col >> 3) ^ (row & 7)) << 3) | (col & 7));
}
__device__ __forceinline__ bf16x8 fragld(const unsigned short* a, int row, int kstep, int quad) {
    return *(const bf16x8*)&a[(row << 6) + ((((kstep << 2) | quad) ^ (row & 7)) << 3)];
}
__device__ __forceinline__ void stage_write(unsigned short* hiA, unsigned short* loA,
                                            int row, int col, float4 f) {
    ushort4 h4, l4;
    h4.x = f32_bf16_rne(f.x); l4.x = f32_bf16_rne(f.x - bf16_f32(h4.x));
    h4.y = f32_bf16_rne(f.y); l4.y = f32_bf16_rne(f.y - bf16_f32(h4.y));
    h4.z = f32_bf16_rne(f.z); l4.z = f32_bf16_rne(f.z - bf16_f32(h4.z));
    h4.w = f32_bf16_rne(f.w); l4.w = f32_bf16_rne(f.w - bf16_f32(h4.w));
    const int o = sw(row, col);
    *(ushort4*)&hiA[o] = h4;
    *(ushort4*)&loA[o] = l4;
}

// ---------------------------------------------------------------------------
// bf16x3 MFMA GEMM: out[b,m,n] = sum_k W[m,k] * X[b,k,n] + bias[m]
// mode 0 (QKV): sel 0 (Q), sel 1 (K) store transposed [B,H,T,KC];
//               sel 2 (V) stores natural [B,C,T].
// mode 1 (out-proj): natural [B,C,T] store.
// ---------------------------------------------------------------------------
#define BM 128
#define BN 64
#define BK 32
#define LDK 40

__global__ __launch_bounds__(256) void gemm3_mfma(
    int mode,
    const float* __restrict__ w0, const float* __restrict__ w1, const float* __restrict__ w2,
    const float* __restrict__ b0, const float* __restrict__ b1, const float* __restrict__ b2,
    const float* __restrict__ x,
    float* __restrict__ o0, float* __restrict__ o1, float* __restrict__ o2)
{
    __shared__ unsigned short Whi[BM][LDK], Wlo[BM][LDK];
    __shared__ unsigned short Xhi[BN][LDK], Xlo[BN][LDK];

    const int tid = threadIdx.x;
    const int bx = blockIdx.x;
    const int by = blockIdx.y;
    const int b  = blockIdx.z;

    const int m_tile = by * BM;
    const int sel = m_tile >> 9;
    const float* W  = sel == 0 ? w0 : (sel == 1 ? w1 : w2);
    const float* Bv = sel == 0 ? b0 : (sel == 1 ? b1 : b2);
    const int m0 = m_tile & 511;
    const int n0 = bx * BN;

    const float* Xb = x + (size_t)b * Cdim * Tdim;

    const int lane = tid & 63, wid = tid >> 6;
    const int wm = (wid & 1) * 64, wn = (wid >> 1) * 32;
    const int l15 = lane & 15, quad = lane >> 4;

    const int wk4 = (tid & 7) * 4;
    const int wmr = tid >> 3;
    const int xn  = tid & 63;
    const int xo  = tid >> 6;

    f32x4 acc[4][2];
    #pragma unroll
    for (int i = 0; i < 4; ++i)
        #pragma unroll
        for (int j = 0; j < 2; ++j) acc[i][j] = (f32x4){0.f, 0.f, 0.f, 0.f};

    for (int k0 = 0; k0 < Cdim; k0 += BK) {
        __syncthreads();

        #pragma unroll
        for (int p = 0; p < 4; ++p) {
            const int m = wmr + p * 32;
            float4 wv = *(const float4*)(W + (size_t)(m0 + m) * Cdim + k0 + wk4);
            ushort4 hi, lo;
            hi.x = f32_bf16_rne(wv.x); lo.x = f32_bf16_rne(wv.x - bf16_f32(hi.x));
            hi.y = f32_bf16_rne(wv.y); lo.y = f32_bf16_rne(wv.y - bf16_f32(hi.y));
            hi.z = f32_bf16_rne(wv.z); lo.z = f32_bf16_rne(wv.z - bf16_f32(hi.z));
            hi.w = f32_bf16_rne(wv.w); lo.w = f32_bf16_rne(wv.w - bf16_f32(hi.w));
            *(ushort4*)&Whi[m][wk4] = hi;
            *(ushort4*)&Wlo[m][wk4] = lo;
        }

        {
            float xv[8];
            #pragma unroll
            for (int kk = 0; kk < 8; ++kk)
                xv[kk] = Xb[(size_t)(k0 + xo * 8 + kk) * Tdim + n0 + xn];
            ushort4 hi0, hi1, lo0, lo1;
            unsigned short h;
            h = f32_bf16_rne(xv[0]); hi0.x = h; lo0.x = f32_bf16_rne(xv[0] - bf16_f32(h));
            h = f32_bf16_rne(xv[1]); hi0.y = h; lo0.y = f32_bf16_rne(xv[1] - bf16_f32(h));
            h = f32_bf16_rne(xv[2]); hi0.z = h; lo0.z = f32_bf16_rne(xv[2] - bf16_f32(h));
            h = f32_bf16_rne(xv[3]); hi0.w = h; lo0.w = f32_bf16_rne(xv[3] - bf16_f32(h));
            h = f32_bf16_rne(xv[4]); hi1.x = h; lo1.x = f32_bf16_rne(xv[4] - bf16_f32(h));
            h = f32_bf16_rne(xv[5]); hi1.y = h; lo1.y = f32_bf16_rne(xv[5] - bf16_f32(h));
            h = f32_bf16_rne(xv[6]); hi1.z = h; lo1.z = f32_bf16_rne(xv[6] - bf16_f32(h));
            h = f32_bf16_rne(xv[7]); hi1.w = h; lo1.w = f32_bf16_rne(xv[7] - bf16_f32(h));
            *(ushort4*)&Xhi[xn][xo * 8]     = hi0;
            *(ushort4*)&Xhi[xn][xo * 8 + 4] = hi1;
            *(ushort4*)&Xlo[xn][xo * 8]     = lo0;
            *(ushort4*)&Xlo[xn][xo * 8 + 4] = lo1;
        }
        __syncthreads();

        bf16x8 ahi[4], alo[4], bhi[2], blo[2];
        #pragma unroll
        for (int mt = 0; mt < 4; ++mt) {
            ahi[mt] = *(const bf16x8*)&Whi[wm + mt * 16 + l15][quad * 8];
            alo[mt] = *(const bf16x8*)&Wlo[wm + mt * 16 + l15][quad * 8];
        }
        #pragma unroll
        for (int nt = 0; nt < 2; ++nt) {
            bhi[nt] = *(const bf16x8*)&Xhi[wn + nt * 16 + l15][quad * 8];
            blo[nt] = *(const bf16x8*)&Xlo[wn + nt * 16 + l15][quad * 8];
        }
        #pragma unroll
        for (int mt = 0; mt < 4; ++mt)
            #pragma unroll
            for (int nt = 0; nt < 2; ++nt) {
                f32x4 c = acc[mt][nt];
                c = __builtin_amdgcn_mfma_f32_16x16x32_bf16(ahi[mt], bhi[nt], c, 0, 0, 0);
                c = __builtin_amdgcn_mfma_f32_16x16x32_bf16(ahi[mt], blo[nt], c, 0, 0, 0);
                c = __builtin_amdgcn_mfma_f32_16x16x32_bf16(alo[mt], bhi[nt], c, 0, 0, 0);
                acc[mt][nt] = c;
            }
    }

    const bool tstore = (mode == 0) && (sel < 2);
    if (tstore) {
        float* Ot = (sel == 0 ? o0 : o1);
        #pragma unroll
        for (int mt = 0; mt < 4; ++mt) {
            const int mv = m0 + wm + mt * 16 + quad * 4;
            const int head = mv >> 6, c0 = mv & 63;
            float bb[4];
            #pragma unroll
            for (int r = 0; r < 4; ++r) bb[r] = Bv[mv + r];
            float* tb = Ot + ((size_t)(b * Hn + head) * Tdim) * KCd;
            #pragma unroll
            for (int nt = 0; nt < 2; ++nt) {
                const int t = n0 + wn + nt * 16 + l15;
                float4 r4;
                r4.x = acc[mt][nt][0] + bb[0];
                r4.y = acc[mt][nt][1] + bb[1];
                r4.z = acc[mt][nt][2] + bb[2];
                r4.w = acc[mt][nt][3] + bb[3];
                *(float4*)(tb + (size_t)t * KCd + c0) = r4;
            }
        }
    } else {
        float* Ob = (sel == 0 ? o0 : (sel == 1 ? o1 : o2)) + (size_t)b * Cdim * Tdim;
        #pragma unroll
        for (int mt = 0; mt < 4; ++mt) {
            const int mb = m0 + wm + mt * 16 + quad * 4;
            float bb[4];
            #pragma unroll
            for (int r = 0; r < 4; ++r) bb[r] = Bv[mb + r];
            #pragma unroll
            for (int nt = 0; nt < 2; ++nt) {
                const int t = n0 + wn + nt * 16 + l15;
                #pragma unroll
                for (int r = 0; r < 4; ++r)
                    Ob[(size_t)(mb + r) * Tdim + t] = acc[mt][nt][r] + bb[r];
            }
        }
    }
}

// ---------------------------------------------------------------------------
// MFMA flash attention with banded relative terms.
// Block: 64 q-rows, 256 threads = 4 waves; wave w owns m-strip [w*16, w*16+16).
// GEMM1: S^T = K·Q^T (A=K tile, B=Q frags hoisted in regs) -> lane l15 = m.
// Online softmax per lane (scalar state), 2 shuffles per reduction.
// GEMM2: O = P·V (A=P from LDS, B=V natural-layout tile). bf16x3 throughout.
// ---------------------------------------------------------------------------
__global__ __launch_bounds__(256) void attn_mfma(
    const float* __restrict__ qT,   // [B,H,T,KC]
    const float* __restrict__ kT,   // [B,H,T,KC]
    const float* __restrict__ v,    // [B,C,T]
    const float* __restrict__ ek,   // [9,64]
    const float* __restrict__ ev,   // [9,64]
    float* __restrict__ ctx)        // [B,C,T]
{
    __shared__ unsigned short qsh[4096], qsl[4096];
    __shared__ unsigned short ksh[4096], ksl[4096];
    __shared__ unsigned short vsh[4096], vsl[4096];
    __shared__ unsigned short psh[4096], psl[4096];
    __shared__ float rk[64 * 12];
    __shared__ float evs[9 * 68];

    const int tid = threadIdx.x;
    const int i0 = blockIdx.x * 64;
    const int h = blockIdx.y, b = blockIdx.z;
    const int lane = tid & 63, w = tid >> 6;
    const int l15 = lane & 15, quad = lane >> 4;

    const float* qTb = qT + (size_t)(b * Hn + h) * Tdim * KCd;
    const float* kTb = kT + (size_t)(b * Hn + h) * Tdim * KCd;
    const float* vb  = v + ((size_t)b * Cdim + h * KCd) * Tdim;
    float* ctxb = ctx + ((size_t)b * Cdim + h * KCd) * Tdim;

    const int sr  = tid >> 2;   // staging row 0..63
    const int scq = tid & 3;    // staging col quarter

    // ---- stage Q tile (rows i0+sr) + evs ----
    #pragma unroll
    for (int u = 0; u < 4; ++u) {
        float4 f = *(const float4*)(qTb + (size_t)(i0 + sr) * KCd + scq * 16 + u * 4);
        stage_write(qsh, qsl, sr, scq * 16 + u * 4, f);
    }
    for (int idx = tid; idx < 576; idx += 256)
        evs[(idx >> 6) * 68 + (idx & 63)] = ev[idx];
    __syncthreads();

    // ---- rk[m][e] = q[m]·ek[e] (raw, pre-scale) ----
    for (int idx = tid; idx < 576; idx += 256) {
        const int m = idx / 9, e = idx - m * 9;
        float s = 0.f;
        for (int c = 0; c < 64; ++c) {
            const int o = sw(m, c);
            s += (bf16_f32(qsh[o]) + bf16_f32(qsl[o])) * ek[e * 64 + c];
        }
        rk[m * 12 + e] = s;
    }

    // ---- hoist Q B-frags (constant across all 16 j-tiles) ----
    bf16x8 qfh[2], qfl[2];
    #pragma unroll
    for (int ks_ = 0; ks_ < 2; ++ks_) {
        qfh[ks_] = fragld(qsh, w * 16 + l15, ks_, quad);
        qfl[ks_] = fragld(qsl, w * 16 + l15, ks_, quad);
    }

    const int m_blk = w * 16 + l15;
    float m_run = -1e30f, l_run = 0.f;
    f32x4 Oc[4];
    #pragma unroll
    for (int ct = 0; ct < 4; ++ct) Oc[ct] = (f32x4){0.f, 0.f, 0.f, 0.f};

    // prefetch tile 0
    float4 kf[4], vf[4];
    #pragma unroll
    for (int u = 0; u < 4; ++u) {
        kf[u] = *(const float4*)(kTb + (size_t)sr * KCd + scq * 16 + u * 4);
        vf[u] = *(const float4*)(vb + (size_t)sr * Tdim + scq * 16 + u * 4);
    }

    for (int t = 0; t < 16; ++t) {
        const int j0 = t << 6;
        __syncthreads();   // D: prev GEMM2 LDS reads done (iter0: rk/evs ready)
        #pragma unroll
        for (int u = 0; u < 4; ++u) {
            stage_write(ksh, ksl, sr, scq * 16 + u * 4, kf[u]);
            stage_write(vsh, vsl, sr, scq * 16 + u * 4, vf[u]);
        }
        __syncthreads();   // A: K/V tile visible

        if (t < 15) {
            const int j1 = j0 + 64;
            #pragma unroll
            for (int u = 0; u < 4; ++u) {
                kf[u] = *(const float4*)(kTb + (size_t)(j1 + sr) * KCd + scq * 16 + u * 4);
                vf[u] = *(const float4*)(vb + (size_t)sr * Tdim + j1 + scq * 16 + u * 4);
            }
        }

        // ---- GEMM1: S^T[j][m], lane: col=m_blk, rows j = jt*16+quad*4+reg ----
        f32x4 Sc[4];
        #pragma unroll
        for (int jt = 0; jt < 4; ++jt) Sc[jt] = (f32x4){0.f, 0.f, 0.f, 0.f};
        #pragma unroll
        for (int ks_ = 0; ks_ < 2; ++ks_) {
            #pragma unroll
            for (int jt = 0; jt < 4; ++jt) {
                bf16x8 ah = fragld(ksh, jt * 16 + l15, ks_, quad);
                bf16x8 al = fragld(ksl, jt * 16 + l15, ks_, quad);
                Sc[jt] = __builtin_amdgcn_mfma_f32_16x16x32_bf16(ah, qfh[ks_], Sc[jt], 0, 0, 0);
                Sc[jt] = __builtin_amdgcn_mfma_f32_16x16x32_bf16(ah, qfl[ks_], Sc[jt], 0, 0, 0);
                Sc[jt] = __builtin_amdgcn_mfma_f32_16x16x32_bf16(al, qfh[ks_], Sc[jt], 0, 0, 0);
            }
        }

        const int dt = j0 - i0;
        const bool diag = (dt >= -67 && dt <= 67);
        if (diag) {   // banded rel-k add (raw, pre-scale)
            #pragma unroll
            for (int jt = 0; jt < 4; ++jt) {
                const int db = dt + jt * 16 + quad * 4 - m_blk;
                #pragma unroll
                for (int r = 0; r < 4; ++r) {
                    const int d = db + r;
                    if ((unsigned)(d + 4) <= 8u) Sc[jt][r] += rk[m_blk * 12 + d + 4];
                }
            }
        }

        // ---- scale + online softmax (row m = m_blk per lane) ----
        float mt = -1e30f;
        #pragma unroll
        for (int jt = 0; jt < 4; ++jt)
            #pragma unroll
            for (int r = 0; r < 4; ++r) {
                Sc[jt][r] *= 0.125f;
                mt = fmaxf(mt, Sc[jt][r]);
            }
        mt = fmaxf(mt, __shfl_xor(mt, 16));
        mt = fmaxf(mt, __shfl_xor(mt, 32));
        const float mn = fmaxf(m_run, mt);
        const float alpha = __expf(m_run - mn);
        float rs = 0.f;
        #pragma unroll
        for (int jt = 0; jt < 4; ++jt)
            #pragma unroll
            for (int r = 0; r < 4; ++r) {
                const float e = __expf(Sc[jt][r] - mn);
                Sc[jt][r] = e;
                rs += e;
            }
        rs += __shfl_xor(rs, 16);
        rs += __shfl_xor(rs, 32);
        l_run = l_run * alpha + rs;
        m_run = mn;

        // ---- write P (A-operand layout [m][j], bf16 hi/lo) ----
        #pragma unroll
        for (int jt = 0; jt < 4; ++jt) {
            ushort4 ph, pl;
            ph.x = f32_bf16_rne(Sc[jt][0]); pl.x = f32_bf16_rne(Sc[jt][0] - bf16_f32(ph.x));
            ph.y = f32_bf16_rne(Sc[jt][1]); pl.y = f32_bf16_rne(Sc[jt][1] - bf16_f32(ph.y));
            ph.z = f32_bf16_rne(Sc[jt][2]); pl.z = f32_bf16_rne(Sc[jt][2] - bf16_f32(ph.z));
            ph.w = f32_bf16_rne(Sc[jt][3]); pl.w = f32_bf16_rne(Sc[jt][3] - bf16_f32(ph.w));
            const int o = sw(m_blk, jt * 16 + quad * 4);
            *(ushort4*)&psh[o] = ph;
            *(ushort4*)&psl[o] = pl;
        }
        __syncthreads();   // C: P visible

        // ---- GEMM2: O[m][c] += P·V ; rescale by alpha first ----
        const float al0 = __shfl(alpha, quad * 4 + 0);
        const float al1 = __shfl(alpha, quad * 4 + 1);
        const float al2 = __shfl(alpha, quad * 4 + 2);
        const float al3 = __shfl(alpha, quad * 4 + 3);
        #pragma unroll
        for (int ct = 0; ct < 4; ++ct) {
            Oc[ct][0] *= al0; Oc[ct][1] *= al1; Oc[ct][2] *= al2; Oc[ct][3] *= al3;
        }
        #pragma unroll
        for (int ks_ = 0; ks_ < 2; ++ks_) {
            bf16x8 pah = fragld(psh, m_blk, ks_, quad);
            bf16x8 pal = fragld(psl, m_blk, ks_, quad);
            #pragma unroll
            for (int ct = 0; ct < 4; ++ct) {
                bf16x8 bh = fragld(vsh, ct * 16 + l15, ks_, quad);
                bf16x8 bl = fragld(vsl, ct * 16 + l15, ks_, quad);
                Oc[ct] = __builtin_amdgcn_mfma_f32_16x16x32_bf16(pah, bh, Oc[ct], 0, 0, 0);
                Oc[ct] = __builtin_amdgcn_mfma_f32_16x16x32_bf16(pah, bl, Oc[ct], 0, 0, 0);
                Oc[ct] = __builtin_amdgcn_mfma_f32_16x16x32_bf16(pal, bh, Oc[ct], 0, 0, 0);
            }
        }

        if (diag) {   // banded rel-v via P in LDS (pre-normalization, alpha-consistent)
            #pragma unroll
            for (int r = 0; r < 4; ++r) {
                const int mrow = w * 16 + quad * 4 + r;
                const int ig = i0 + mrow;
                #pragma unroll
                for (int e = 0; e < 9; ++e) {
                    const int jl = ig + e - 4 - j0;
                    if ((unsigned)jl < 64u) {
                        const int o = sw(mrow, jl);
                        const float p = bf16_f32(psh[o]) + bf16_f32(psl[o]);
                        #pragma unroll
                        for (int ct = 0; ct < 4; ++ct)
                            Oc[ct][r] += p * evs[e * 68 + ct * 16 + l15];
                    }
                }
            }
        }
    }

    // ---- epilogue: normalize rows, store ctx natural [B,C,T] ----
    const float rlv = 1.f / l_run;
    const float rl0 = __shfl(rlv, quad * 4 + 0);
    const float rl1 = __shfl(rlv, quad * 4 + 1);
    const float rl2 = __shfl(rlv, quad * 4 + 2);
    const float rl3 = __shfl(rlv, quad * 4 + 3);
    #pragma unroll
    for (int ct = 0; ct < 4; ++ct) {
        float4 o4;
        o4.x = Oc[ct][0] * rl0;
        o4.y = Oc[ct][1] * rl1;
        o4.z = Oc[ct][2] * rl2;
        o4.w = Oc[ct][3] * rl3;
        *(float4*)(ctxb + (size_t)(ct * 16 + l15) * Tdim + i0 + w * 16 + quad * 4) = o4;
    }
}

// ---------------------------------------------------------------------------
extern "C" void kernel_launch(void* const* d_in, const int* in_sizes, int n_in,
                              void* d_out, int out_size, void* d_ws, size_t ws_size,
                              hipStream_t stream) {
    const float* x  = (const float*)d_in[0];
    const float* wq = (const float*)d_in[1];
    const float* bq = (const float*)d_in[2];
    const float* wk = (const float*)d_in[3];
    const float* bk = (const float*)d_in[4];
    const float* wv = (const float*)d_in[5];
    const float* bv = (const float*)d_in[6];
    const float* wo = (const float*)d_in[7];
    const float* bo = (const float*)d_in[8];
    const float* ek = (const float*)d_in[9];
    const float* ev = (const float*)d_in[10];
    float* out = (float*)d_out;

    const size_t plane = (size_t)Bdim * Cdim * Tdim;  // 2M floats = 8 MB
    float* qTbuf = (float*)d_ws;          // [B,H,T,KC]
    float* kTbuf = qTbuf + plane;         // [B,H,T,KC]
    float* vbuf  = kTbuf + plane;         // [B,C,T]
    float* cbuf  = vbuf + plane;          // [B,C,T]

    // QKV projection: Q,K transposed; V natural
    gemm3_mfma<<<dim3(Tdim / BN, 1536 / BM, Bdim), 256, 0, stream>>>(
        0, wq, wk, wv, bq, bk, bv, x, qTbuf, kTbuf, vbuf);

    // MFMA flash attention with banded relative terms
    attn_mfma<<<dim3(Tdim / 64, Hn, Bdim), 256, 0, stream>>>(
        qTbuf, kTbuf, vbuf, ek, ev, cbuf);

    // output projection (natural store)
    gemm3_mfma<<<dim3(Tdim / BN, Cdim / BM, Bdim), 256, 0, stream>>>(
        1, wo, wo, wo, bo, bo, bo, cbuf, out, out, out);
}